// Round 1
// baseline (26.519 us; speedup 1.0000x reference)
//
#include <hip/hip_runtime.h>
#include <math.h>

// Graph2GraphModel: lidar-chain GCN (3 layers, HID=64) -> masked mean pool
// -> Wp(64x512) -> relu(Wm1 512x1024) -> Wm2(1024x200).
// All fp32. Structure: 4 small kernels; GCN split over 24 blocks with a
// 3-node halo (chain graph => no cross-block deps within 3 layers).

#define NSCAN 360
#define HID 64
#define NB1 24      // k1 blocks
#define CHUNK 15    // nodes per k1 block (24*15 = 360)
#define EXT 21      // CHUNK + 6 halo

// ws layout (floats)
#define WS_PARTIAL 0                   // NB1*HID
#define WS_C       (NB1*HID)           // 512
#define WS_M1      (WS_C + 512)        // 1024

__device__ __forceinline__ void loadW64(int t, const float* __restrict__ W,
                                        float (*sW)[HID]) {
  // 64x64 = 4096 floats = 1024 float4
  const float4* src = reinterpret_cast<const float4*>(W);
  float4* dst = reinterpret_cast<float4*>(&sW[0][0]);
  for (int i = t; i < 1024; i += 256) dst[i] = src[i];
}

__device__ __forceinline__ void matmul64(int t, int glo, int ghi, int base,
                                         const float (*sh)[HID],
                                         float (*shw)[HID],
                                         const float (*sW)[HID]) {
  const int cnt = ghi - glo;
  const int off = glo - base;
  for (int g4 = t; g4 < cnt * 16; g4 += 256) {
    const int nl = off + (g4 >> 4);
    const int j4 = (g4 & 15) << 2;
    float a0 = 0.f, a1 = 0.f, a2 = 0.f, a3 = 0.f;
#pragma unroll 16
    for (int k = 0; k < HID; ++k) {
      const float hv = sh[nl][k];                     // broadcast within wave
      const float4 w = *reinterpret_cast<const float4*>(&sW[k][j4]);
      a0 = fmaf(hv, w.x, a0);
      a1 = fmaf(hv, w.y, a1);
      a2 = fmaf(hv, w.z, a2);
      a3 = fmaf(hv, w.w, a3);
    }
    float4 r; r.x = a0; r.y = a1; r.z = a2; r.w = a3;
    *reinterpret_cast<float4*>(&shw[nl][j4]) = r;
  }
}

__device__ __forceinline__ void agg_relu(int t, int olo, int ohi, int base,
                                         const float (*shw)[HID],
                                         float (*sh)[HID],
                                         const float* sinv,
                                         const float* scoef,
                                         const float* __restrict__ bias) {
  const int cnt = ohi - olo;
  for (int o = t; o < cnt * HID; o += 256) {
    const int nl = o >> 6, j = o & 63;
    const int n = olo + nl;
    float v = sinv[n] * sinv[n] * shw[n - base][j];
    if (n > 0)         v += scoef[n - 1] * shw[n - 1 - base][j];
    if (n < NSCAN - 1) v += scoef[n]     * shw[n + 1 - base][j];
    v += bias[j];
    sh[n - base][j] = fmaxf(v, 0.f);
  }
}

__global__ __launch_bounds__(256) void k1_gcn(
    const float* __restrict__ x,
    const float* __restrict__ W1, const float* __restrict__ b1,
    const float* __restrict__ W2, const float* __restrict__ b2,
    const float* __restrict__ W3, const float* __restrict__ b3,
    float* __restrict__ partial) {
  __shared__ float smask[NSCAN];
  __shared__ float spair[NSCAN - 1];
  __shared__ float sinv[NSCAN];
  __shared__ float scoef[NSCAN - 1];
  __shared__ float snod[NSCAN][2];
  __shared__ float sh[EXT][HID];
  __shared__ float shw[EXT][HID];
  __shared__ float sW[HID][HID];
  __shared__ float sred[4][HID];

  const int t = threadIdx.x;
  const int b = blockIdx.x;

  // ---- lidar prep (full 360, redundant per block; trivial) ----
  for (int i = t; i < NSCAN; i += 256) {
    const float l = x[i];                     // x[0, i]
    smask[i] = (l != 1.0f) ? 1.0f : 0.0f;
    const double a = (double)i * (6.283185307179586476925287 / 359.0);
    snod[i][0] = l * (float)cos(a);
    snod[i][1] = l * (float)sin(a);
  }
  __syncthreads();
  for (int i = t; i < NSCAN - 1; i += 256) spair[i] = smask[i] * smask[i + 1];
  __syncthreads();
  for (int i = t; i < NSCAN; i += 256) {
    float deg = smask[i];
    if (i > 0)         deg += spair[i - 1];
    if (i < NSCAN - 1) deg += spair[i];
    sinv[i] = (deg > 0.f) ? 1.0f / sqrtf(deg) : 0.f;
  }
  __syncthreads();
  for (int i = t; i < NSCAN - 1; i += 256)
    scoef[i] = spair[i] * sinv[i] * sinv[i + 1];

  const int s = b * CHUNK, e = s + CHUNK;
  const int lo3 = max(0, s - 3), hi3 = min(NSCAN, e + 3);
  const int lo2 = max(0, s - 2), hi2 = min(NSCAN, e + 2);
  const int lo1 = max(0, s - 1), hi1 = min(NSCAN, e + 1);
  const int base = lo3;
  __syncthreads();

  // ---- layer 1: hW1 = nodes @ W1 over [lo3,hi3); also stage W2 ----
  loadW64(t, W2, sW);
  {
    const int cnt = hi3 - lo3;
    for (int o = t; o < cnt * HID; o += 256) {
      const int nl = o >> 6, j = o & 63;
      const int n = base + nl;
      shw[nl][j] = fmaf(snod[n][0], W1[j], snod[n][1] * W1[HID + j]);
    }
  }
  __syncthreads();
  agg_relu(t, lo2, hi2, base, shw, sh, sinv, scoef, b1);   // h1 on [lo2,hi2)
  __syncthreads();

  // ---- layer 2 ----
  matmul64(t, lo2, hi2, base, sh, shw, sW);
  __syncthreads();
  agg_relu(t, lo1, hi1, base, shw, sh, sinv, scoef, b2);   // h2 on [lo1,hi1)
  loadW64(t, W3, sW);   // safe: matmul2 finished at the sync above
  __syncthreads();

  // ---- layer 3 ----
  matmul64(t, lo1, hi1, base, sh, shw, sW);
  __syncthreads();
  agg_relu(t, s, e, base, shw, sh, sinv, scoef, b3);       // h3 on [s,e)
  __syncthreads();

  // ---- partial masked pool over own chunk ----
  const int jl = t & 63, g = t >> 6;
  float acc = 0.f;
  for (int n = s + g; n < e; n += 4) acc += sh[n - base][jl] * smask[n];
  sred[g][jl] = acc;
  __syncthreads();
  if (t < HID)
    partial[b * HID + t] = sred[0][t] + sred[1][t] + sred[2][t] + sred[3][t];
}

__global__ __launch_bounds__(512) void k2_pool_proj(
    const float* __restrict__ x,
    const float* __restrict__ Wp, const float* __restrict__ bp,
    const float* __restrict__ partial, float* __restrict__ c) {
  __shared__ float sgemb[HID];
  __shared__ float snv[8];
  const int t = threadIdx.x;

  // n_valid = sum(mask)
  float m = 0.f;
  if (t < NSCAN) m = (x[t] != 1.0f) ? 1.0f : 0.0f;
  for (int off = 32; off; off >>= 1) m += __shfl_down(m, off, 64);
  if ((t & 63) == 0) snv[t >> 6] = m;
  __syncthreads();

  if (t < HID) {
    float nv = 0.f;
#pragma unroll
    for (int w = 0; w < 8; ++w) nv += snv[w];
    float sum = 0.f;
#pragma unroll
    for (int bb = 0; bb < NB1; ++bb) sum += partial[bb * HID + t];
    sgemb[t] = sum / nv;
  }
  __syncthreads();

  float acc = bp[t];
#pragma unroll 16
  for (int k = 0; k < HID; ++k) acc = fmaf(sgemb[k], Wp[k * 512 + t], acc);
  c[t] = acc;
}

__global__ __launch_bounds__(256) void k3a_hidden(
    const float* __restrict__ c, const float* __restrict__ Wm1,
    const float* __restrict__ bm1, float* __restrict__ m1) {
  __shared__ float sc[512];
  __shared__ float sred[4][64];
  const int t = threadIdx.x;
  for (int i = t; i < 512; i += 256) sc[i] = c[i];
  __syncthreads();
  const int jl = t & 63, g = t >> 6;
  const int j = blockIdx.x * 64 + jl;
  float acc = 0.f;
  const int k0 = g * 128;
#pragma unroll 8
  for (int k = k0; k < k0 + 128; ++k)
    acc = fmaf(sc[k], Wm1[k * 1024 + j], acc);
  sred[g][jl] = acc;
  __syncthreads();
  if (t < 64) {
    const int jj = blockIdx.x * 64 + t;
    const float v = sred[0][t] + sred[1][t] + sred[2][t] + sred[3][t] + bm1[jj];
    m1[jj] = fmaxf(v, 0.f);
  }
}

__global__ __launch_bounds__(256) void k3b_out(
    const float* __restrict__ m1, const float* __restrict__ Wm2,
    const float* __restrict__ bm2, float* __restrict__ out) {
  __shared__ float sws[4];
  const int t = threadIdx.x;
  const int j = blockIdx.x;   // 0..199
  float acc = 0.f;
#pragma unroll
  for (int it = 0; it < 4; ++it) {
    const int k = t + it * 256;
    acc = fmaf(m1[k], Wm2[k * 200 + j], acc);
  }
  for (int off = 32; off; off >>= 1) acc += __shfl_down(acc, off, 64);
  if ((t & 63) == 0) sws[t >> 6] = acc;
  __syncthreads();
  if (t == 0) out[j] = sws[0] + sws[1] + sws[2] + sws[3] + bm2[j];
}

extern "C" void kernel_launch(void* const* d_in, const int* in_sizes, int n_in,
                              void* d_out, int out_size, void* d_ws,
                              size_t ws_size, hipStream_t stream) {
  const float* x   = (const float*)d_in[0];
  const float* W1  = (const float*)d_in[1];
  const float* b1  = (const float*)d_in[2];
  const float* W2  = (const float*)d_in[3];
  const float* b2  = (const float*)d_in[4];
  const float* W3  = (const float*)d_in[5];
  const float* b3  = (const float*)d_in[6];
  const float* Wp  = (const float*)d_in[7];
  const float* bp  = (const float*)d_in[8];
  const float* Wm1 = (const float*)d_in[9];
  const float* bm1 = (const float*)d_in[10];
  const float* Wm2 = (const float*)d_in[11];
  const float* bm2 = (const float*)d_in[12];

  float* ws = (float*)d_ws;
  float* partial = ws + WS_PARTIAL;
  float* c       = ws + WS_C;
  float* m1      = ws + WS_M1;
  float* out     = (float*)d_out;

  k1_gcn<<<NB1, 256, 0, stream>>>(x, W1, b1, W2, b2, W3, b3, partial);
  k2_pool_proj<<<1, 512, 0, stream>>>(x, Wp, bp, partial, c);
  k3a_hidden<<<16, 256, 0, stream>>>(c, Wm1, bm1, m1);
  k3b_out<<<200, 256, 0, stream>>>(m1, Wm2, bm2, out);
}